// Round 1
// baseline (2233.755 us; speedup 1.0000x reference)
//
#include <hip/hip_runtime.h>
#include <math.h>

// ReasoningCell: B=256, D=1024, NH=16, HD=64, S_q=128, S_obj=256, S_rel=512.
// Key transform: fold wk into the query (softmax shift-invariance kills bk),
// and apply wv AFTER the attention-weighted sum over raw features (linearity,
// sum(attn)=1 passes bv through). This removes the 962-GFLOP K/V projection
// GEMMs; the kernel becomes a ~940 MB streaming problem + small MFMA work.

typedef __attribute__((ext_vector_type(8))) __bf16 bf16x8;
typedef __attribute__((ext_vector_type(4))) float floatx4;

__device__ __forceinline__ unsigned short f2b(float x) {
  return __builtin_bit_cast(unsigned short, (__bf16)x);
}
__device__ __forceinline__ uint2 pack4(float4 v) {
  uint2 r;
  r.x = (unsigned)f2b(v.x) | ((unsigned)f2b(v.y) << 16);
  r.y = (unsigned)f2b(v.z) | ((unsigned)f2b(v.w) << 16);
  return r;
}
// 8 consecutive bf16 from LDS (8B-aligned) -> fragment
__device__ __forceinline__ bf16x8 ldsfrag(const unsigned short* p) {
  union { unsigned u[4]; bf16x8 v; } r;
  uint2 a = *(const uint2*)p;
  uint2 b = *(const uint2*)(p + 4);
  r.u[0] = a.x; r.u[1] = a.y; r.u[2] = b.x; r.u[3] = b.y;
  return r.v;
}
__device__ __forceinline__ floatx4 mfma16(bf16x8 a, bf16x8 b, floatx4 c) {
  // A[m=lane&15][k=(lane>>4)*8+j], B[k=(lane>>4)*8+j][n=lane&15],
  // D[row=(lane>>4)*4+r][col=lane&15]  (m89/m91/m120-verified layouts)
  return __builtin_amdgcn_mfma_f32_16x16x32_bf16(a, b, c, 0, 0, 0);
}
__device__ __forceinline__ float act_apply(float x, int act) {
  if (act == 1) return 0.5f * x * (1.0f + erff(x * 0.70710678118654752f)); // exact gelu
  if (act == 2) return 1.0f / (1.0f + __expf(-x));                        // sigmoid
  return x;
}

// ---------------------------------------------------------------------------
// Generic MFMA linear: Y[m,n] = act(alpha * sum_k X[m,k]*Wsel + bias[n])
// transB=0: Wsel = W[n,k] (row-major (N,K));  transB=1: Wsel = W[k,n] ((K,N))
// headMode: X element offset += (n0/64)*1024 (per-head ctx projection)
// z-batch: per-z element offsets sXz/sWz/sYz (used for the wk fold, Z=16)
// Requires: M%64==0, N%64==0, K%32==0.  Block=256 (4 waves), tile 64x64.
// ---------------------------------------------------------------------------
__global__ __launch_bounds__(256)
void linear_kernel(const float* __restrict__ X, const float* __restrict__ W,
                   const float* __restrict__ bias, float* __restrict__ Y,
                   int M, int N, int K, int lda, int ldw, int ldy,
                   int act, float alpha, int transB, int headMode,
                   long sXz, long sWz, long sYz) {
  int n0 = blockIdx.x * 64;
  int m0 = blockIdx.y * 64;
  int z  = blockIdx.z;
  X += (long)z * sXz; W += (long)z * sWz; Y += (long)z * sYz;
  if (headMode) X += (n0 >> 6) * 1024;

  __shared__ __attribute__((aligned(16))) unsigned short Xt[64 * 36]; // pitch 36 bf16
  __shared__ __attribute__((aligned(16))) unsigned short Wt[64 * 36];

  int tid = threadIdx.x;
  int lane = tid & 63, wid = tid >> 6;
  int l15 = lane & 15, q4 = lane >> 4;
  int mt = (wid >> 1) * 2, nt = (wid & 1) * 2; // wave's 32x32 quadrant
  floatx4 c[2][2] = {};

  for (int k0 = 0; k0 < K; k0 += 32) {
    __syncthreads();
    // stage X tile 64x32 fp32 -> bf16
#pragma unroll
    for (int i = 0; i < 2; i++) {
      int idx = tid + i * 256;          // 512 float4
      int row = idx >> 3, c4 = idx & 7;
      float4 v = *(const float4*)(X + (long)(m0 + row) * lda + k0 + c4 * 4);
      *(uint2*)&Xt[row * 36 + c4 * 4] = pack4(v);
    }
    if (!transB) {
#pragma unroll
      for (int i = 0; i < 2; i++) {
        int idx = tid + i * 256;
        int row = idx >> 3, c4 = idx & 7;
        float4 v = *(const float4*)(W + (long)(n0 + row) * ldw + k0 + c4 * 4);
        *(uint2*)&Wt[row * 36 + c4 * 4] = pack4(v);
      }
    } else {
      // W is (K,N): read 32k x 64n, store transposed
#pragma unroll
      for (int i = 0; i < 2; i++) {
        int idx = tid + i * 256;
        int kk = idx >> 4, c4 = idx & 15;
        float4 v = *(const float4*)(W + (long)(k0 + kk) * ldw + n0 + c4 * 4);
        int nb = c4 * 4;
        Wt[(nb + 0) * 36 + kk] = f2b(v.x);
        Wt[(nb + 1) * 36 + kk] = f2b(v.y);
        Wt[(nb + 2) * 36 + kk] = f2b(v.z);
        Wt[(nb + 3) * 36 + kk] = f2b(v.w);
      }
    }
    __syncthreads();
    bf16x8 a0 = ldsfrag(&Xt[((mt + 0) * 16 + l15) * 36 + q4 * 8]);
    bf16x8 a1 = ldsfrag(&Xt[((mt + 1) * 16 + l15) * 36 + q4 * 8]);
    bf16x8 b0 = ldsfrag(&Wt[((nt + 0) * 16 + l15) * 36 + q4 * 8]);
    bf16x8 b1 = ldsfrag(&Wt[((nt + 1) * 16 + l15) * 36 + q4 * 8]);
    c[0][0] = mfma16(a0, b0, c[0][0]);
    c[0][1] = mfma16(a0, b1, c[0][1]);
    c[1][0] = mfma16(a1, b0, c[1][0]);
    c[1][1] = mfma16(a1, b1, c[1][1]);
  }
#pragma unroll
  for (int i = 0; i < 2; i++)
#pragma unroll
    for (int j = 0; j < 2; j++) {
      int gmB = m0 + (mt + i) * 16 + q4 * 4;
      int gn  = n0 + (nt + j) * 16 + l15;
      float bv = bias ? bias[gn] : 0.0f;
#pragma unroll
      for (int r = 0; r < 4; r++) {
        float val = alpha * c[i][j][r] + bv;
        val = act_apply(val, act);
        Y[(long)(gmB + r) * ldy + gn] = val;
      }
    }
}

// ---------------------------------------------------------------------------
// Fused single-query attention (per-b block): scores = qt(16xD,bf16) @ kv^T,
// unnormalized exp (safe: |score| << 10 with 0.02-scale weights), ctx = P@kv
// via MFMA, normalize by l at end. Raw scores kept in LDS for attn_mean.
// qt pre-scaled by 1/sqrt(hd). ctx may alias qt (per-b disjoint; qt fully
// staged to LDS before ctx writes). Block = 512 threads (8 waves).
// ---------------------------------------------------------------------------
__global__ __launch_bounds__(512)
void attn_kernel(const float* qt, const float* __restrict__ kv,
                 const int* __restrict__ mask, float* ctx, float* attn_mean,
                 int S) {
  const int PQ = 1028; // bf16 pitch: 2056 B rows (8B-aligned, bank-stagger)
  __shared__ __attribute__((aligned(16))) unsigned short qtile[16 * 1028];  // 32,896 B
  __shared__ __attribute__((aligned(16))) unsigned short kvtile[32 * 1028]; // 65,792 B
  __shared__ __attribute__((aligned(16))) float sco[16 * 513];              // 32,832 B
  __shared__ __attribute__((aligned(16))) unsigned short P[16 * 36];        //  1,152 B
  __shared__ __attribute__((aligned(16))) float scratch[8 * 256];           //  8,192 B
  __shared__ __attribute__((aligned(16))) float red[16 * 33];               //  2,112 B
  __shared__ float linv[16];

  int b = blockIdx.x;
  int tid = threadIdx.x, lane = tid & 63, wid = tid >> 6;
  int l15 = lane & 15, q4 = lane >> 4;
  int pitchS = S + 1;

  // stage q-tilde (16 x 1024) -> bf16 LDS
  const float* qb = qt + (long)b * 16384;
  for (int idx = tid; idx < 16 * 256; idx += 512) {
    int row = idx >> 8, c4 = idx & 255;
    float4 v = *(const float4*)(qb + row * 1024 + c4 * 4);
    *(uint2*)&qtile[row * PQ + c4 * 4] = pack4(v);
  }

  floatx4 acc[8] = {}; // ctx accumulator: this wave owns d in [wid*128, wid*128+128)
  const float* kvb = kv + (long)b * S * 1024;
  int sntile = wid & 1, skq = wid >> 1; // scores: s-subtile + K-quarter per wave

  for (int s0 = 0; s0 < S; s0 += 32) {
    __syncthreads(); // protect kvtile/P from previous iteration's readers
    // stage kv tile (32 x 1024) fp32 -> bf16
#pragma unroll
    for (int i = 0; i < 16; i++) {
      int idx = tid + i * 512;
      int row = idx >> 8, c4 = idx & 255;
      float4 v = *(const float4*)(kvb + (long)(s0 + row) * 1024 + c4 * 4);
      *(uint2*)&kvtile[row * PQ + c4 * 4] = pack4(v);
    }
    __syncthreads();
    // scores partials: wave computes 16h x 16s over its 256-wide K quarter
    floatx4 cp = {};
#pragma unroll
    for (int ks = 0; ks < 8; ks++) {
      int k0 = skq * 256 + ks * 32 + q4 * 8;
      bf16x8 a  = ldsfrag(&qtile[l15 * PQ + k0]);
      bf16x8 bb = ldsfrag(&kvtile[(sntile * 16 + l15) * PQ + k0]);
      cp = mfma16(a, bb, cp);
    }
#pragma unroll
    for (int r = 0; r < 4; r++)
      scratch[wid * 256 + (q4 * 4 + r) * 16 + l15] = cp[r];
    __syncthreads();
    // reduce K-quarters, mask, store raw score + P = exp(raw) (bf16)
    {
      int h = tid >> 5, sc = tid & 31;
      int nt2 = sc >> 4, scc = sc & 15;
      float raw = 0.0f;
#pragma unroll
      for (int q2 = 0; q2 < 4; q2++)
        raw += scratch[(q2 * 2 + nt2) * 256 + h * 16 + scc];
      if (mask && mask[(long)b * S + s0 + sc] == 0) raw = -1e9f;
      sco[h * pitchS + s0 + sc] = raw;
      P[h * 36 + sc] = f2b(__expf(raw));
    }
    __syncthreads();
    // ctx accumulate: D[h, d] += P(16x32) @ kv(32xD), wave owns 128 d-cols
    {
      bf16x8 a = ldsfrag(&P[l15 * 36 + q4 * 8]);
#pragma unroll
      for (int nt = 0; nt < 8; nt++) {
        int d = wid * 128 + nt * 16 + l15;
        union { bf16x8 v; unsigned short u[8]; } bb;
        int kb = q4 * 8;
#pragma unroll
        for (int j = 0; j < 8; j++) bb.u[j] = kvtile[(kb + j) * PQ + d];
        acc[nt] = mfma16(a, bb.v, acc[nt]);
      }
    }
  }
  __syncthreads();
  // denominator l[h] = sum_s exp(score)
  {
    int h = tid >> 5, j = tid & 31;
    float p = 0.0f;
    for (int s = j; s < S; s += 32) p += __expf(sco[h * pitchS + s]);
    red[h * 33 + j] = p;
  }
  __syncthreads();
  if (tid < 16) {
    float l = 0.0f;
    for (int j = 0; j < 32; j++) l += red[tid * 33 + j];
    linv[tid] = 1.0f / l;
  }
  __syncthreads();
  if (attn_mean) {
    for (int s = tid; s < S; s += 512) {
      float sum = 0.0f;
#pragma unroll
      for (int h = 0; h < 16; h++) sum += __expf(sco[h * pitchS + s]) * linv[h];
      attn_mean[(long)b * S + s] = sum * (1.0f / 16.0f);
    }
  }
  // write normalized ctx
  float* cb = ctx + (long)b * 16384;
#pragma unroll
  for (int nt = 0; nt < 8; nt++) {
    int d = wid * 128 + nt * 16 + l15;
#pragma unroll
    for (int r = 0; r < 4; r++) {
      int h = q4 * 4 + r;
      cb[h * 1024 + d] = acc[nt][r] * linv[h];
    }
  }
}

// ---------------------------------------------------------------------------
// LayerNorm over 1024 cols. mode 0: x = x1 + x2; mode 1: x = g*x1 + (1-g)*x2
// ---------------------------------------------------------------------------
__global__ __launch_bounds__(256)
void ln_kernel(float* __restrict__ out, const float* __restrict__ x1,
               const float* __restrict__ x2, const float* __restrict__ gate,
               const float* __restrict__ g, const float* __restrict__ b,
               int mode) {
  int row = blockIdx.x, tid = threadIdx.x;
  long base = (long)row * 1024 + tid * 4;
  float4 a = *(const float4*)(x1 + base);
  float4 c = *(const float4*)(x2 + base);
  float v0, v1, v2, v3;
  if (mode == 0) {
    v0 = a.x + c.x; v1 = a.y + c.y; v2 = a.z + c.z; v3 = a.w + c.w;
  } else {
    float4 gt = *(const float4*)(gate + base);
    v0 = gt.x * a.x + (1.0f - gt.x) * c.x;
    v1 = gt.y * a.y + (1.0f - gt.y) * c.y;
    v2 = gt.z * a.z + (1.0f - gt.z) * c.z;
    v3 = gt.w * a.w + (1.0f - gt.w) * c.w;
  }
  float s = v0 + v1 + v2 + v3;
  float q = v0 * v0 + v1 * v1 + v2 * v2 + v3 * v3;
  for (int off = 32; off > 0; off >>= 1) {
    s += __shfl_down(s, off);
    q += __shfl_down(q, off);
  }
  __shared__ float rs[4], rq[4];
  int lane = tid & 63, wid = tid >> 6;
  if (lane == 0) { rs[wid] = s; rq[wid] = q; }
  __syncthreads();
  float S0 = rs[0] + rs[1] + rs[2] + rs[3];
  float Q0 = rq[0] + rq[1] + rq[2] + rq[3];
  float mean = S0 * (1.0f / 1024.0f);
  float var = Q0 * (1.0f / 1024.0f) - mean * mean;
  float rstd = rsqrtf(var + 1e-5f);
  float4 gv = *(const float4*)(g + tid * 4);
  float4 bv = *(const float4*)(b + tid * 4);
  float4 o;
  o.x = (v0 - mean) * rstd * gv.x + bv.x;
  o.y = (v1 - mean) * rstd * gv.y + bv.y;
  o.z = (v2 - mean) * rstd * gv.z + bv.z;
  o.w = (v3 - mean) * rstd * gv.w + bv.w;
  *(float4*)(out + base) = o;
}

// copy 256 rows x 1024 cols into strided destination (for concat buffers)
__global__ __launch_bounds__(256)
void copy_cols(float* __restrict__ dst, const float* __restrict__ src,
               int ldd, int lsrc) {
  int idx = blockIdx.x * 256 + threadIdx.x; // 65536 float4
  int row = idx >> 8, c4 = idx & 255;
  *(float4*)(dst + (long)row * ldd + c4 * 4) =
      *(const float4*)(src + (long)row * lsrc + c4 * 4);
}

// ---------------------------------------------------------------------------
extern "C" void kernel_launch(void* const* d_in, const int* in_sizes, int n_in,
                              void* d_out, int out_size, void* d_ws,
                              size_t ws_size, hipStream_t stream) {
  const float* control = (const float*)d_in[0];
  const float* memry   = (const float*)d_in[1];
  const float* qemb    = (const float*)d_in[2];
  const float* objf    = (const float*)d_in[3];
  const float* relf    = (const float*)d_in[4];
  const int*   qmask   = (const int*)d_in[5];
  const float* c_qkv_w = (const float*)d_in[6];
  const float* c_qkv_b = (const float*)d_in[7];
  const float* c_out_w = (const float*)d_in[8];
  const float* c_out_b = (const float*)d_in[9];
  const float* c_up_w1 = (const float*)d_in[10];
  const float* c_up_b1 = (const float*)d_in[11];
  const float* c_up_w2 = (const float*)d_in[12];
  const float* c_up_b2 = (const float*)d_in[13];
  const float* c_pr_w  = (const float*)d_in[14];
  const float* c_pr_b  = (const float*)d_in[15];
  const float* c_ln_g  = (const float*)d_in[16];
  const float* c_ln_b  = (const float*)d_in[17];
  const float* o_qkv_w = (const float*)d_in[18];
  const float* o_qkv_b = (const float*)d_in[19];
  const float* o_out_w = (const float*)d_in[20];
  const float* o_out_b = (const float*)d_in[21];
  const float* r_qkv_w = (const float*)d_in[22];
  const float* r_qkv_b = (const float*)d_in[23];
  const float* r_out_w = (const float*)d_in[24];
  const float* r_out_b = (const float*)d_in[25];
  const float* rc_w1   = (const float*)d_in[26];
  const float* rc_b1   = (const float*)d_in[27];
  const float* rc_w2   = (const float*)d_in[28];
  const float* rc_b2   = (const float*)d_in[29];
  const float* rg_w    = (const float*)d_in[30];
  const float* rg_b    = (const float*)d_in[31];
  const float* r_ln_g  = (const float*)d_in[32];
  const float* r_ln_b  = (const float*)d_in[33];
  const float* wg_w    = (const float*)d_in[34];
  const float* wg_b    = (const float*)d_in[35];
  const float* wt_w1   = (const float*)d_in[36];
  const float* wt_b1   = (const float*)d_in[37];
  const float* wt_w2   = (const float*)d_in[38];
  const float* wt_b2   = (const float*)d_in[39];
  const float* w_ln_g  = (const float*)d_in[40];
  const float* w_ln_b  = (const float*)d_in[41];

  float* out_nc = (float*)d_out;           // new_control (256x1024)
  float* out_nm = out_nc + 262144;         // new_memory
  float* out_oa = out_nm + 262144;         // obj_attn (256x256)
  float* out_ra = out_oa + 65536;          // rel_attn (256x512)

  float* ws = (float*)d_ws;                // ~29.4 MB used
  float* qh   = ws;                        // 256x1024
  float* qt   = qh + 262144;               // 256x16x1024 (q-tilde; aliased ctx)
  float* ctxb = qt;                        // alias: safe (per-b disjoint in attn)
  float* vout = qt + 4194304;              // 256x1024
  float* attq = vout + 262144;
  float* tmp1 = attq + 262144;
  float* tmp2 = tmp1 + 262144;
  float* tmp3 = tmp2 + 262144;
  float* cat  = tmp3 + 262144;             // 256x3072 max
  float* oinf = cat + 786432;
  float* rinf = oinf + 262144;
  float* rdout= rinf + 262144;

  dim3 blk256(256), blk512(512);
  auto lin = [&](const float* X, const float* W, const float* bias, float* Y,
                 int N, int K, int lda, int ldw, int ldy, int act, float alpha,
                 int transB, int headMode, int Z, long sXz, long sWz, long sYz) {
    dim3 g(N / 64, 4, Z); // M=256 always
    linear_kernel<<<g, blk256, 0, stream>>>(X, W, bias, Y, 256, N, K, lda, ldw,
                                            ldy, act, alpha, transB, headMode,
                                            sXz, sWz, sYz);
  };
  auto attn = [&](const float* qtp, const float* kvp, const int* mp, float* cp,
                  float* am, int S) {
    attn_kernel<<<dim3(256), blk512, 0, stream>>>(qtp, kvp, mp, cp, am, S);
  };
  auto ln = [&](float* o, const float* x1, const float* x2, const float* gt,
                const float* g, const float* b, int mode) {
    ln_kernel<<<dim3(256), blk256, 0, stream>>>(o, x1, x2, gt, g, b, mode);
  };
  auto cpy = [&](float* dst, const float* src, int ldd) {
    copy_cols<<<dim3(256), blk256, 0, stream>>>(dst, src, ldd, 1024);
  };

  // ---------------- Control unit ----------------
  lin(control, c_qkv_w, c_qkv_b, qh, 1024, 1024, 1024, 1024, 1024, 0, 1.f, 0, 0, 1, 0, 0, 0);
  lin(qh, c_qkv_w + 1024 * 1024, nullptr, qt, 1024, 64, 1024, 1024, 16384,
      0, 0.125f, 1, 0, 16, 64, 64 * 1024, 1024);              // q-tilde (wk fold, /sqrt(hd))
  attn(qt, qemb, qmask, ctxb, nullptr, 128);
  lin(ctxb, c_qkv_w + 2048 * 1024, c_qkv_b + 2048, vout, 1024, 1024, 16384, 1024, 1024,
      0, 1.f, 0, 1, 1, 0, 0, 0);                              // per-head wv
  lin(vout, c_out_w, c_out_b, attq, 1024, 1024, 1024, 1024, 1024, 0, 1.f, 0, 0, 1, 0, 0, 0);
  cpy(cat, control, 2048);
  cpy(cat + 1024, attq, 2048);
  lin(cat, c_up_w1, c_up_b1, tmp1, 1024, 2048, 2048, 2048, 1024, 1, 1.f, 0, 0, 1, 0, 0, 0);
  lin(tmp1, c_up_w2, c_up_b2, tmp2, 1024, 1024, 1024, 1024, 1024, 0, 1.f, 0, 0, 1, 0, 0, 0);
  lin(attq, c_pr_w, c_pr_b, tmp3, 1024, 1024, 1024, 1024, 1024, 0, 1.f, 0, 0, 1, 0, 0, 0);
  ln(out_nc, tmp2, tmp3, nullptr, c_ln_g, c_ln_b, 0);         // new_control

  // ---------------- Read unit: objects ----------------
  lin(out_nc, o_qkv_w, o_qkv_b, qh, 1024, 1024, 1024, 1024, 1024, 0, 1.f, 0, 0, 1, 0, 0, 0);
  lin(qh, o_qkv_w + 1024 * 1024, nullptr, qt, 1024, 64, 1024, 1024, 16384,
      0, 0.125f, 1, 0, 16, 64, 64 * 1024, 1024);
  attn(qt, objf, nullptr, ctxb, out_oa, 256);
  lin(ctxb, o_qkv_w + 2048 * 1024, o_qkv_b + 2048, vout, 1024, 1024, 16384, 1024, 1024,
      0, 1.f, 0, 1, 1, 0, 0, 0);
  lin(vout, o_out_w, o_out_b, oinf, 1024, 1024, 1024, 1024, 1024, 0, 1.f, 0, 0, 1, 0, 0, 0);

  // ---------------- Read unit: relations ----------------
  lin(out_nc, r_qkv_w, r_qkv_b, qh, 1024, 1024, 1024, 1024, 1024, 0, 1.f, 0, 0, 1, 0, 0, 0);
  lin(qh, r_qkv_w + 1024 * 1024, nullptr, qt, 1024, 64, 1024, 1024, 16384,
      0, 0.125f, 1, 0, 16, 64, 64 * 1024, 1024);
  attn(qt, relf, nullptr, ctxb, out_ra, 512);
  lin(ctxb, r_qkv_w + 2048 * 1024, r_qkv_b + 2048, vout, 1024, 1024, 16384, 1024, 1024,
      0, 1.f, 0, 1, 1, 0, 0, 0);
  lin(vout, r_out_w, r_out_b, rinf, 1024, 1024, 1024, 1024, 1024, 0, 1.f, 0, 0, 1, 0, 0, 0);

  // ---------------- Read combine/gate ----------------
  cpy(cat, oinf, 2048);
  cpy(cat + 1024, rinf, 2048);
  lin(cat, rc_w1, rc_b1, tmp1, 1024, 2048, 2048, 2048, 1024, 1, 1.f, 0, 0, 1, 0, 0, 0);
  lin(tmp1, rc_w2, rc_b2, tmp2, 1024, 1024, 1024, 1024, 1024, 0, 1.f, 0, 0, 1, 0, 0, 0); // combined
  cpy(cat, tmp2, 2048);
  cpy(cat + 1024, memry, 2048);
  lin(cat, rg_w, rg_b, tmp3, 1024, 2048, 2048, 2048, 1024, 2, 1.f, 0, 0, 1, 0, 0, 0);    // gate
  ln(rdout, tmp2, memry, tmp3, r_ln_g, r_ln_b, 1);            // read_output

  // ---------------- Write unit ----------------
  cpy(cat, memry, 3072);
  cpy(cat + 1024, rdout, 3072);
  cpy(cat + 2048, out_nc, 3072);
  lin(cat, wg_w, wg_b, tmp3, 1024, 3072, 3072, 3072, 1024, 2, 1.f, 0, 0, 1, 0, 0, 0);    // wg
  cpy(cat, rdout, 2048);
  cpy(cat + 1024, out_nc, 2048);
  lin(cat, wt_w1, wt_b1, tmp1, 1024, 2048, 2048, 2048, 1024, 1, 1.f, 0, 0, 1, 0, 0, 0);
  lin(tmp1, wt_w2, wt_b2, tmp2, 1024, 1024, 1024, 1024, 1024, 0, 1.f, 0, 0, 1, 0, 0, 0); // update
  ln(out_nm, tmp2, memry, tmp3, w_ln_g, w_ln_b, 1);           // new_memory
}